// Round 8
// baseline (2144.175 us; speedup 1.0000x reference)
//
#include <hip/hip_runtime.h>
#include <hip/hip_bf16.h>

#define DE 128
#define SB 256          // scan chunk
#define NPB 16          // nodes per block (8 groups x 2 nodes each)

typedef float f4 __attribute__((ext_vector_type(4)));

// ---------------------------------------------------------------------------
// CSR build: histogram over all 3 relations in one launch
// ---------------------------------------------------------------------------
__global__ void count_all(const int* __restrict__ d0, const int* __restrict__ d1,
                          const int* __restrict__ d2, int* __restrict__ cnt,
                          int N, int n0, int n1, int n2) {
    int i = blockIdx.x * blockDim.x + threadIdx.x;
    int total = n0 + n1 + n2;
    if (i >= total) return;
    int r, j;
    if (i < n0)            { r = 0; j = i; }
    else if (i < n0 + n1)  { r = 1; j = i - n0; }
    else                   { r = 2; j = i - n0 - n1; }
    const int* d = (r == 0) ? d0 : (r == 1) ? d1 : d2;
    atomicAdd(&cnt[(size_t)r * N + d[j]], 1);
}

// block-local exclusive scan of cnt -> off, block totals -> bs
__global__ void scan1(const int* __restrict__ cnt, int* __restrict__ off,
                      int* __restrict__ bs, int N, int nchunks) {
    int r = blockIdx.y, c = blockIdx.x, tid = threadIdx.x;
    int i = c * SB + tid;
    __shared__ int s[SB];
    int v = (i < N) ? cnt[(size_t)r * N + i] : 0;
    s[tid] = v; __syncthreads();
    for (int d = 1; d < SB; d <<= 1) {
        int tv = (tid >= d) ? s[tid - d] : 0;
        __syncthreads();
        s[tid] += tv;
        __syncthreads();
    }
    if (i < N) off[(size_t)r * N + i] = s[tid] - v;     // exclusive within chunk
    if (tid == SB - 1) bs[r * nchunks + c] = s[tid];
}

// scan the chunk totals (nchunks <= 512)
__global__ void scan2(int* __restrict__ bs, int nchunks) {
    int r = blockIdx.x, tid = threadIdx.x;
    __shared__ int s[512];
    int v = (tid < nchunks) ? bs[r * nchunks + tid] : 0;
    s[tid] = v; __syncthreads();
    for (int d = 1; d < 512; d <<= 1) {
        int tv = (tid >= d) ? s[tid - d] : 0;
        __syncthreads();
        s[tid] += tv;
        __syncthreads();
    }
    if (tid < nchunks) bs[r * nchunks + tid] = s[tid] - v;  // exclusive
}

// add chunk offsets, produce final exclusive offsets + cursor copy
__global__ void scan3(int* __restrict__ off, const int* __restrict__ bs,
                      int* __restrict__ cur, int N, int nchunks) {
    int r = blockIdx.y;
    int i = blockIdx.x * SB + threadIdx.x;
    if (i < N) {
        int v = off[(size_t)r * N + i] + bs[r * nchunks + blockIdx.x];
        off[(size_t)r * N + i] = v;
        cur[(size_t)r * N + i] = v;
    }
}

// bucket-fill edge ids sorted by destination, all 3 relations in one launch
__global__ void fill_all(const int* __restrict__ d0, const int* __restrict__ d1,
                         const int* __restrict__ d2, int* __restrict__ cur,
                         int* __restrict__ eid, int N, int n0, int n1, int n2) {
    int i = blockIdx.x * blockDim.x + threadIdx.x;
    int total = n0 + n1 + n2;
    if (i >= total) return;
    int r, j, base;
    if (i < n0)            { r = 0; j = i;            base = 0; }
    else if (i < n0 + n1)  { r = 1; j = i - n0;       base = n0; }
    else                   { r = 2; j = i - n0 - n1;  base = n0 + n1; }
    const int* d = (r == 0) ? d0 : (r == 1) ? d1 : d2;
    int node = d[j];
    int p = atomicAdd(&cur[(size_t)r * N + node], 1);
    eid[base + p] = j;
}

// ---------------------------------------------------------------------------
// Fused: gather-mean (CSR) + tanh-gate attention + projection.
// 256 threads = 8 groups x 32 threads; each group owns TWO nodes (gathered
// serially). MLP batches both nodes' rows per weight load (z[6][4]) so each
// W1/W3 element fetched once per block covers 16 nodes -> weight L2 traffic
// halves vs NPB=8 (R7 diagnosis: kernel is L2-BW-bound on weight streams).
// Groups remain wave-local: no __syncthreads anywhere.
// ---------------------------------------------------------------------------
__global__ __launch_bounds__(256) void node_fused(
        const float* __restrict__ E0, const float* __restrict__ E1,
        const float* __restrict__ E2,
        const int* __restrict__ eid,   // [sum nE], per-relation bases
        const int* __restrict__ off,   // [3,N]
        const int* __restrict__ cnt,   // [3,N]
        const float* __restrict__ W1, const float* __restrict__ W2,
        const float* __restrict__ W3,
        float* __restrict__ out, int N, int base1, int base2) {
    const int g = threadIdx.x >> 5;      // group 0..7
    const int t = threadIdx.x & 31;      // lane in group

    __shared__ float Ysh[NPB][3][DE];    // 24 KB
    __shared__ float OYsh[NPB][DE];      // 8 KB

    const float* Es[3] = { E0, E1, E2 };
    const int ebase[3] = { 0, base1, base2 };

    // ---- gather + mean for the group's two nodes
    for (int n2 = 0; n2 < 2; ++n2) {
        const int ln = g * 2 + n2;
        int node = blockIdx.x * NPB + ln;
        if (node >= N) node = N - 1;     // clamp (store guarded below)

        #pragma unroll
        for (int r = 0; r < 3; ++r) {
            int start = off[(size_t)r * N + node];
            int deg   = cnt[(size_t)r * N + node];
            const int* el = eid + ebase[r] + start;
            const float* E = Es[r];
            f4 acc = {0.f, 0.f, 0.f, 0.f};

            int k = 0;
            for (; k + 8 <= deg; k += 8) {
                int e0 = el[k + 0], e1 = el[k + 1], e2 = el[k + 2], e3 = el[k + 3];
                int e4 = el[k + 4], e5 = el[k + 5], e6 = el[k + 6], e7 = el[k + 7];
                f4 v0 = __builtin_nontemporal_load(
                    reinterpret_cast<const f4*>(E + (size_t)e0 * DE + t * 4));
                f4 v1 = __builtin_nontemporal_load(
                    reinterpret_cast<const f4*>(E + (size_t)e1 * DE + t * 4));
                f4 v2 = __builtin_nontemporal_load(
                    reinterpret_cast<const f4*>(E + (size_t)e2 * DE + t * 4));
                f4 v3 = __builtin_nontemporal_load(
                    reinterpret_cast<const f4*>(E + (size_t)e3 * DE + t * 4));
                f4 v4 = __builtin_nontemporal_load(
                    reinterpret_cast<const f4*>(E + (size_t)e4 * DE + t * 4));
                f4 v5 = __builtin_nontemporal_load(
                    reinterpret_cast<const f4*>(E + (size_t)e5 * DE + t * 4));
                f4 v6 = __builtin_nontemporal_load(
                    reinterpret_cast<const f4*>(E + (size_t)e6 * DE + t * 4));
                f4 v7 = __builtin_nontemporal_load(
                    reinterpret_cast<const f4*>(E + (size_t)e7 * DE + t * 4));
                acc += ((v0 + v1) + (v2 + v3)) + ((v4 + v5) + (v6 + v7));
            }
            if (k + 4 <= deg) {
                int e0 = el[k + 0], e1 = el[k + 1], e2 = el[k + 2], e3 = el[k + 3];
                f4 v0 = __builtin_nontemporal_load(
                    reinterpret_cast<const f4*>(E + (size_t)e0 * DE + t * 4));
                f4 v1 = __builtin_nontemporal_load(
                    reinterpret_cast<const f4*>(E + (size_t)e1 * DE + t * 4));
                f4 v2 = __builtin_nontemporal_load(
                    reinterpret_cast<const f4*>(E + (size_t)e2 * DE + t * 4));
                f4 v3 = __builtin_nontemporal_load(
                    reinterpret_cast<const f4*>(E + (size_t)e3 * DE + t * 4));
                acc += (v0 + v1) + (v2 + v3);
                k += 4;
            }
            for (; k < deg; ++k) {
                int e = el[k];
                f4 v = __builtin_nontemporal_load(
                    reinterpret_cast<const f4*>(E + (size_t)e * DE + t * 4));
                acc += v;
            }

            float inv = 1.0f / fmaxf((float)deg, 1.0f);
            acc *= inv;
            *reinterpret_cast<f4*>(&Ysh[ln][r][t * 4]) = acc;
        }
    }

    // ---- z[q][j]: q = (n2*3 + r), cols 4t+j; one w load feeds 24 FMA
    float z[6][4] = {{0,0,0,0},{0,0,0,0},{0,0,0,0},{0,0,0,0},{0,0,0,0},{0,0,0,0}};
    const int ln0 = g * 2;
    for (int d0 = 0; d0 < DE; d0 += 4) {
        f4 y[6];
        #pragma unroll
        for (int q = 0; q < 6; ++q)
            y[q] = *reinterpret_cast<const f4*>(&Ysh[ln0 + (q >> 1 ? (q >= 3) : 0)][0][0]); // placeholder
        // (explicit to avoid any dynamic indexing pitfalls)
        y[0] = *reinterpret_cast<const f4*>(&Ysh[ln0 + 0][0][d0]);
        y[1] = *reinterpret_cast<const f4*>(&Ysh[ln0 + 0][1][d0]);
        y[2] = *reinterpret_cast<const f4*>(&Ysh[ln0 + 0][2][d0]);
        y[3] = *reinterpret_cast<const f4*>(&Ysh[ln0 + 1][0][d0]);
        y[4] = *reinterpret_cast<const f4*>(&Ysh[ln0 + 1][1][d0]);
        y[5] = *reinterpret_cast<const f4*>(&Ysh[ln0 + 1][2][d0]);
        #pragma unroll
        for (int dd = 0; dd < 4; ++dd) {
            int d = d0 + dd;
            f4 w = *reinterpret_cast<const f4*>(W1 + (size_t)d * DE + t * 4);
            #pragma unroll
            for (int q = 0; q < 6; ++q) {
                float a = y[q][dd];
                #pragma unroll
                for (int j = 0; j < 4; ++j) z[q][j] = fmaf(a, w[j], z[q][j]);
            }
        }
    }

    // ---- scores: e_q = sum_o tanh(z_q[o]) * W2[o]; reduce over 32 lanes
    f4 w2v = *reinterpret_cast<const f4*>(W2 + t * 4);
    float s[6] = {0, 0, 0, 0, 0, 0};
    #pragma unroll
    for (int q = 0; q < 6; ++q) {
        #pragma unroll
        for (int j = 0; j < 4; ++j) s[q] = fmaf(tanhf(z[q][j]), w2v[j], s[q]);
    }
    #pragma unroll
    for (int m = 16; m >= 1; m >>= 1) {
        #pragma unroll
        for (int q = 0; q < 6; ++q) s[q] += __shfl_xor(s[q], m);
    }

    // ---- softmax over relations, per node; OY -> LDS (cols 4t..4t+3)
    #pragma unroll
    for (int n2 = 0; n2 < 2; ++n2) {
        float e0 = s[n2 * 3 + 0], e1 = s[n2 * 3 + 1], e2 = s[n2 * 3 + 2];
        float mx = fmaxf(e0, fmaxf(e1, e2));
        float x0 = __expf(e0 - mx), x1 = __expf(e1 - mx), x2 = __expf(e2 - mx);
        float inv = 1.0f / (x0 + x1 + x2);
        float a0 = x0 * inv, a1 = x1 * inv, a2 = x2 * inv;
        const int ln = ln0 + n2;
        f4 y0 = *reinterpret_cast<const f4*>(&Ysh[ln][0][t * 4]);
        f4 y1 = *reinterpret_cast<const f4*>(&Ysh[ln][1][t * 4]);
        f4 y2 = *reinterpret_cast<const f4*>(&Ysh[ln][2][t * 4]);
        f4 oy = a0 * y0 + a1 * y1 + a2 * y2;
        *reinterpret_cast<f4*>(&OYsh[ln][t * 4]) = oy;
    }

    // ---- out = OY @ W3, both nodes per weight load (o[2][4])
    f4 o0 = {0.f, 0.f, 0.f, 0.f};
    f4 o1 = {0.f, 0.f, 0.f, 0.f};
    for (int d0 = 0; d0 < DE; d0 += 4) {
        f4 oy0 = *reinterpret_cast<const f4*>(&OYsh[ln0 + 0][d0]);
        f4 oy1 = *reinterpret_cast<const f4*>(&OYsh[ln0 + 1][d0]);
        #pragma unroll
        for (int dd = 0; dd < 4; ++dd) {
            int d = d0 + dd;
            f4 w = *reinterpret_cast<const f4*>(W3 + (size_t)d * DE + t * 4);
            float a0 = oy0[dd], a1 = oy1[dd];
            #pragma unroll
            for (int j = 0; j < 4; ++j) {
                o0[j] = fmaf(a0, w[j], o0[j]);
                o1[j] = fmaf(a1, w[j], o1[j]);
            }
        }
    }
    {
        int node0 = blockIdx.x * NPB + ln0;
        int node1 = node0 + 1;
        if (node0 < N)
            *reinterpret_cast<f4*>(out + (size_t)node0 * DE + t * 4) = o0;
        if (node1 < N)
            *reinterpret_cast<f4*>(out + (size_t)node1 * DE + t * 4) = o1;
    }
}

// ---------------------------------------------------------------------------
// launch
// ---------------------------------------------------------------------------
extern "C" void kernel_launch(void* const* d_in, const int* in_sizes, int n_in,
                              void* d_out, int out_size, void* d_ws, size_t ws_size,
                              hipStream_t stream) {
    const float* E_C = (const float*)d_in[0];
    const float* E_D = (const float*)d_in[1];
    const float* E_M = (const float*)d_in[2];
    const int* dst_C = (const int*)d_in[3];
    const int* dst_D = (const int*)d_in[4];
    const int* dst_M = (const int*)d_in[5];
    const float* W1 = (const float*)d_in[7];
    const float* W2 = (const float*)d_in[8];
    const float* W3 = (const float*)d_in[9];
    float* out = (float*)d_out;

    const int N = out_size / DE;                     // 100000
    const int nE[3] = { in_sizes[3], in_sizes[4], in_sizes[5] };
    const int NEtot = nE[0] + nE[1] + nE[2];
    const int nchunks = (N + SB - 1) / SB;           // 391 for N=100000

    // workspace (ints): eid[NEtot] | cnt[3N] | off[3N] | cur[3N] | bs[3*nchunks]
    int* eid = (int*)d_ws;
    int* cnt = eid + NEtot;
    int* off = cnt + 3 * (size_t)N;
    int* cur = off + 3 * (size_t)N;
    int* bs  = cur + 3 * (size_t)N;

    (void)hipMemsetAsync(cnt, 0, 3 * (size_t)N * sizeof(int), stream);

    {
        int blocks = (NEtot + 255) / 256;
        count_all<<<blocks, 256, 0, stream>>>(dst_C, dst_D, dst_M, cnt,
                                              N, nE[0], nE[1], nE[2]);
    }

    dim3 g1(nchunks, 3);
    scan1<<<g1, SB, 0, stream>>>(cnt, off, bs, N, nchunks);
    scan2<<<3, 512, 0, stream>>>(bs, nchunks);
    scan3<<<g1, SB, 0, stream>>>(off, bs, cur, N, nchunks);

    {
        int blocks = (NEtot + 255) / 256;
        fill_all<<<blocks, 256, 0, stream>>>(dst_C, dst_D, dst_M, cur, eid,
                                             N, nE[0], nE[1], nE[2]);
    }

    int nblocks = (N + NPB - 1) / NPB;
    node_fused<<<nblocks, 256, 0, stream>>>(
        E_C, E_D, E_M, eid, off, cnt, W1, W2, W3, out,
        N, nE[0], nE[0] + nE[1]);
}

// Round 9
// 892.884 us; speedup vs baseline: 2.4014x; 2.4014x over previous
//
#include <hip/hip_runtime.h>
#include <hip/hip_bf16.h>

#define DE 128
#define SB 256          // scan chunk
#define NPB 16          // nodes per block (8 groups x 2 nodes, gathered serially)

typedef float f4 __attribute__((ext_vector_type(4)));

// ---------------------------------------------------------------------------
// CSR build: histogram over all 3 relations in one launch
// ---------------------------------------------------------------------------
__global__ void count_all(const int* __restrict__ d0, const int* __restrict__ d1,
                          const int* __restrict__ d2, int* __restrict__ cnt,
                          int N, int n0, int n1, int n2) {
    int i = blockIdx.x * blockDim.x + threadIdx.x;
    int total = n0 + n1 + n2;
    if (i >= total) return;
    int r, j;
    if (i < n0)            { r = 0; j = i; }
    else if (i < n0 + n1)  { r = 1; j = i - n0; }
    else                   { r = 2; j = i - n0 - n1; }
    const int* d = (r == 0) ? d0 : (r == 1) ? d1 : d2;
    atomicAdd(&cnt[(size_t)r * N + d[j]], 1);
}

// block-local exclusive scan of cnt -> off, block totals -> bs
__global__ void scan1(const int* __restrict__ cnt, int* __restrict__ off,
                      int* __restrict__ bs, int N, int nchunks) {
    int r = blockIdx.y, c = blockIdx.x, tid = threadIdx.x;
    int i = c * SB + tid;
    __shared__ int s[SB];
    int v = (i < N) ? cnt[(size_t)r * N + i] : 0;
    s[tid] = v; __syncthreads();
    for (int d = 1; d < SB; d <<= 1) {
        int tv = (tid >= d) ? s[tid - d] : 0;
        __syncthreads();
        s[tid] += tv;
        __syncthreads();
    }
    if (i < N) off[(size_t)r * N + i] = s[tid] - v;     // exclusive within chunk
    if (tid == SB - 1) bs[r * nchunks + c] = s[tid];
}

// scan the chunk totals (nchunks <= 512)
__global__ void scan2(int* __restrict__ bs, int nchunks) {
    int r = blockIdx.x, tid = threadIdx.x;
    __shared__ int s[512];
    int v = (tid < nchunks) ? bs[r * nchunks + tid] : 0;
    s[tid] = v; __syncthreads();
    for (int d = 1; d < 512; d <<= 1) {
        int tv = (tid >= d) ? s[tid - d] : 0;
        __syncthreads();
        s[tid] += tv;
        __syncthreads();
    }
    if (tid < nchunks) bs[r * nchunks + tid] = s[tid] - v;  // exclusive
}

// add chunk offsets, produce final exclusive offsets + cursor copy
__global__ void scan3(int* __restrict__ off, const int* __restrict__ bs,
                      int* __restrict__ cur, int N, int nchunks) {
    int r = blockIdx.y;
    int i = blockIdx.x * SB + threadIdx.x;
    if (i < N) {
        int v = off[(size_t)r * N + i] + bs[r * nchunks + blockIdx.x];
        off[(size_t)r * N + i] = v;
        cur[(size_t)r * N + i] = v;
    }
}

// bucket-fill edge ids sorted by destination, all 3 relations in one launch
__global__ void fill_all(const int* __restrict__ d0, const int* __restrict__ d1,
                         const int* __restrict__ d2, int* __restrict__ cur,
                         int* __restrict__ eid, int N, int n0, int n1, int n2) {
    int i = blockIdx.x * blockDim.x + threadIdx.x;
    int total = n0 + n1 + n2;
    if (i >= total) return;
    int r, j, base;
    if (i < n0)            { r = 0; j = i;            base = 0; }
    else if (i < n0 + n1)  { r = 1; j = i - n0;       base = n0; }
    else                   { r = 2; j = i - n0 - n1;  base = n0 + n1; }
    const int* d = (r == 0) ? d0 : (r == 1) ? d1 : d2;
    int node = d[j];
    int p = atomicAdd(&cur[(size_t)r * N + node], 1);
    eid[base + p] = j;
}

// ---------------------------------------------------------------------------
// Fused: gather-mean (CSR) + tanh-gate attention + projection.
// 256 threads = 8 groups x 32 lanes; each group owns TWO nodes.
// Gather: one R7-style body inside a NOT-unrolled loop over the 2 nodes
// (R8 lesson: duplicating the unrolled gather body spilled, VGPR 256).
// MLP: 6 rows (2 nodes x 3 rel) batched per f4 weight load -> 24 FMA/load,
// halving W1/W3 L2 traffic vs R7. y values come from per-d scalar LDS
// broadcasts, not register arrays. Groups stay wave-local: no barriers.
// ---------------------------------------------------------------------------
__global__ __launch_bounds__(256) void node_fused(
        const float* __restrict__ E0, const float* __restrict__ E1,
        const float* __restrict__ E2,
        const int* __restrict__ eid,   // [sum nE], per-relation bases
        const int* __restrict__ off,   // [3,N]
        const int* __restrict__ cnt,   // [3,N]
        const float* __restrict__ W1, const float* __restrict__ W2,
        const float* __restrict__ W3,
        float* __restrict__ out, int N, int base1, int base2) {
    const int g = threadIdx.x >> 5;      // group 0..7
    const int t = threadIdx.x & 31;      // lane in group
    const int ln0 = g * 2;
    const int ln1 = ln0 + 1;

    __shared__ float Ysh[NPB][3][DE];    // 24 KB
    __shared__ float OYsh[NPB][DE];      // 8 KB

    const float* Es[3] = { E0, E1, E2 };
    const int ebase[3] = { 0, base1, base2 };

    // ---- gather + mean for the group's two nodes (loop NOT unrolled)
    #pragma unroll 1
    for (int n2 = 0; n2 < 2; ++n2) {
        const int ln = ln0 + n2;
        int node = blockIdx.x * NPB + ln;
        if (node >= N) node = N - 1;     // clamp; final stores are guarded

        #pragma unroll
        for (int r = 0; r < 3; ++r) {
            int start = off[(size_t)r * N + node];
            int deg   = cnt[(size_t)r * N + node];
            const int* el = eid + ebase[r] + start;
            const float* E = Es[r];
            f4 acc = {0.f, 0.f, 0.f, 0.f};

            int k = 0;
            for (; k + 8 <= deg; k += 8) {
                int e0 = el[k + 0], e1 = el[k + 1], e2 = el[k + 2], e3 = el[k + 3];
                int e4 = el[k + 4], e5 = el[k + 5], e6 = el[k + 6], e7 = el[k + 7];
                f4 v0 = __builtin_nontemporal_load(
                    reinterpret_cast<const f4*>(E + (size_t)e0 * DE + t * 4));
                f4 v1 = __builtin_nontemporal_load(
                    reinterpret_cast<const f4*>(E + (size_t)e1 * DE + t * 4));
                f4 v2 = __builtin_nontemporal_load(
                    reinterpret_cast<const f4*>(E + (size_t)e2 * DE + t * 4));
                f4 v3 = __builtin_nontemporal_load(
                    reinterpret_cast<const f4*>(E + (size_t)e3 * DE + t * 4));
                f4 v4 = __builtin_nontemporal_load(
                    reinterpret_cast<const f4*>(E + (size_t)e4 * DE + t * 4));
                f4 v5 = __builtin_nontemporal_load(
                    reinterpret_cast<const f4*>(E + (size_t)e5 * DE + t * 4));
                f4 v6 = __builtin_nontemporal_load(
                    reinterpret_cast<const f4*>(E + (size_t)e6 * DE + t * 4));
                f4 v7 = __builtin_nontemporal_load(
                    reinterpret_cast<const f4*>(E + (size_t)e7 * DE + t * 4));
                acc += ((v0 + v1) + (v2 + v3)) + ((v4 + v5) + (v6 + v7));
            }
            if (k + 4 <= deg) {
                int e0 = el[k + 0], e1 = el[k + 1], e2 = el[k + 2], e3 = el[k + 3];
                f4 v0 = __builtin_nontemporal_load(
                    reinterpret_cast<const f4*>(E + (size_t)e0 * DE + t * 4));
                f4 v1 = __builtin_nontemporal_load(
                    reinterpret_cast<const f4*>(E + (size_t)e1 * DE + t * 4));
                f4 v2 = __builtin_nontemporal_load(
                    reinterpret_cast<const f4*>(E + (size_t)e2 * DE + t * 4));
                f4 v3 = __builtin_nontemporal_load(
                    reinterpret_cast<const f4*>(E + (size_t)e3 * DE + t * 4));
                acc += (v0 + v1) + (v2 + v3);
                k += 4;
            }
            for (; k < deg; ++k) {
                int e = el[k];
                f4 v = __builtin_nontemporal_load(
                    reinterpret_cast<const f4*>(E + (size_t)e * DE + t * 4));
                acc += v;
            }

            float inv = 1.0f / fmaxf((float)deg, 1.0f);
            acc *= inv;
            *reinterpret_cast<f4*>(&Ysh[ln][r][t * 4]) = acc;
        }
    }

    // ---- z GEMM: 6 rows x 4 cols per thread; one f4 weight load -> 24 FMA
    f4 z0 = {0,0,0,0}, z1 = {0,0,0,0}, z2 = {0,0,0,0};
    f4 z3 = {0,0,0,0}, z4 = {0,0,0,0}, z5 = {0,0,0,0};
    {
        const float* w1p = W1 + t * 4;
        #pragma unroll 4
        for (int d = 0; d < DE; ++d) {
            f4 w = *reinterpret_cast<const f4*>(w1p + (size_t)d * DE);
            float a0 = Ysh[ln0][0][d], a1 = Ysh[ln0][1][d], a2 = Ysh[ln0][2][d];
            float b0 = Ysh[ln1][0][d], b1 = Ysh[ln1][1][d], b2 = Ysh[ln1][2][d];
            z0 += a0 * w; z1 += a1 * w; z2 += a2 * w;
            z3 += b0 * w; z4 += b1 * w; z5 += b2 * w;
        }
    }

    // ---- scores: e_q = sum_o tanh(z_q[o]) * W2[o]; reduce over 32 lanes
    f4 w2v = *reinterpret_cast<const f4*>(W2 + t * 4);
    float s0 = 0.f, s1 = 0.f, s2 = 0.f, s3 = 0.f, s4 = 0.f, s5 = 0.f;
    #pragma unroll
    for (int j = 0; j < 4; ++j) {
        s0 = fmaf(tanhf(z0[j]), w2v[j], s0);
        s1 = fmaf(tanhf(z1[j]), w2v[j], s1);
        s2 = fmaf(tanhf(z2[j]), w2v[j], s2);
        s3 = fmaf(tanhf(z3[j]), w2v[j], s3);
        s4 = fmaf(tanhf(z4[j]), w2v[j], s4);
        s5 = fmaf(tanhf(z5[j]), w2v[j], s5);
    }
    #pragma unroll
    for (int m = 16; m >= 1; m >>= 1) {
        s0 += __shfl_xor(s0, m); s1 += __shfl_xor(s1, m); s2 += __shfl_xor(s2, m);
        s3 += __shfl_xor(s3, m); s4 += __shfl_xor(s4, m); s5 += __shfl_xor(s5, m);
    }

    // ---- softmax per node; OY -> LDS (cols 4t..4t+3)
    {
        float mx = fmaxf(s0, fmaxf(s1, s2));
        float x0 = __expf(s0 - mx), x1 = __expf(s1 - mx), x2 = __expf(s2 - mx);
        float inv = 1.0f / (x0 + x1 + x2);
        f4 y0 = *reinterpret_cast<const f4*>(&Ysh[ln0][0][t * 4]);
        f4 y1 = *reinterpret_cast<const f4*>(&Ysh[ln0][1][t * 4]);
        f4 y2 = *reinterpret_cast<const f4*>(&Ysh[ln0][2][t * 4]);
        f4 oy = (x0 * inv) * y0 + (x1 * inv) * y1 + (x2 * inv) * y2;
        *reinterpret_cast<f4*>(&OYsh[ln0][t * 4]) = oy;
    }
    {
        float mx = fmaxf(s3, fmaxf(s4, s5));
        float x0 = __expf(s3 - mx), x1 = __expf(s4 - mx), x2 = __expf(s5 - mx);
        float inv = 1.0f / (x0 + x1 + x2);
        f4 y0 = *reinterpret_cast<const f4*>(&Ysh[ln1][0][t * 4]);
        f4 y1 = *reinterpret_cast<const f4*>(&Ysh[ln1][1][t * 4]);
        f4 y2 = *reinterpret_cast<const f4*>(&Ysh[ln1][2][t * 4]);
        f4 oy = (x0 * inv) * y0 + (x1 * inv) * y1 + (x2 * inv) * y2;
        *reinterpret_cast<f4*>(&OYsh[ln1][t * 4]) = oy;
    }

    // ---- out = OY @ W3, both nodes per weight load
    f4 o0 = {0,0,0,0}, o1 = {0,0,0,0};
    {
        const float* w3p = W3 + t * 4;
        #pragma unroll 4
        for (int d = 0; d < DE; ++d) {
            f4 w = *reinterpret_cast<const f4*>(w3p + (size_t)d * DE);
            float a = OYsh[ln0][d];
            float b = OYsh[ln1][d];
            o0 += a * w;
            o1 += b * w;
        }
    }
    {
        int node0 = blockIdx.x * NPB + ln0;
        int node1 = node0 + 1;
        if (node0 < N)
            *reinterpret_cast<f4*>(out + (size_t)node0 * DE + t * 4) = o0;
        if (node1 < N)
            *reinterpret_cast<f4*>(out + (size_t)node1 * DE + t * 4) = o1;
    }
}

// ---------------------------------------------------------------------------
// launch
// ---------------------------------------------------------------------------
extern "C" void kernel_launch(void* const* d_in, const int* in_sizes, int n_in,
                              void* d_out, int out_size, void* d_ws, size_t ws_size,
                              hipStream_t stream) {
    const float* E_C = (const float*)d_in[0];
    const float* E_D = (const float*)d_in[1];
    const float* E_M = (const float*)d_in[2];
    const int* dst_C = (const int*)d_in[3];
    const int* dst_D = (const int*)d_in[4];
    const int* dst_M = (const int*)d_in[5];
    const float* W1 = (const float*)d_in[7];
    const float* W2 = (const float*)d_in[8];
    const float* W3 = (const float*)d_in[9];
    float* out = (float*)d_out;

    const int N = out_size / DE;                     // 100000
    const int nE[3] = { in_sizes[3], in_sizes[4], in_sizes[5] };
    const int NEtot = nE[0] + nE[1] + nE[2];
    const int nchunks = (N + SB - 1) / SB;           // 391 for N=100000

    // workspace (ints): eid[NEtot] | cnt[3N] | off[3N] | cur[3N] | bs[3*nchunks]
    int* eid = (int*)d_ws;
    int* cnt = eid + NEtot;
    int* off = cnt + 3 * (size_t)N;
    int* cur = off + 3 * (size_t)N;
    int* bs  = cur + 3 * (size_t)N;

    (void)hipMemsetAsync(cnt, 0, 3 * (size_t)N * sizeof(int), stream);

    {
        int blocks = (NEtot + 255) / 256;
        count_all<<<blocks, 256, 0, stream>>>(dst_C, dst_D, dst_M, cnt,
                                              N, nE[0], nE[1], nE[2]);
    }

    dim3 g1(nchunks, 3);
    scan1<<<g1, SB, 0, stream>>>(cnt, off, bs, N, nchunks);
    scan2<<<3, 512, 0, stream>>>(bs, nchunks);
    scan3<<<g1, SB, 0, stream>>>(off, bs, cur, N, nchunks);

    {
        int blocks = (NEtot + 255) / 256;
        fill_all<<<blocks, 256, 0, stream>>>(dst_C, dst_D, dst_M, cur, eid,
                                             N, nE[0], nE[1], nE[2]);
    }

    int nblocks = (N + NPB - 1) / NPB;
    node_fused<<<nblocks, 256, 0, stream>>>(
        E_C, E_D, E_M, eid, off, cnt, W1, W2, W3, out,
        N, nE[0], nE[0] + nE[1]);
}

// Round 10
// 856.111 us; speedup vs baseline: 2.5046x; 1.0430x over previous
//
#include <hip/hip_runtime.h>
#include <hip/hip_bf16.h>

#define DE 128
#define SB 256          // scan chunk
#define NPB 16          // nodes per block (8 groups x 2 nodes, gathered serially)

typedef float f4 __attribute__((ext_vector_type(4)));

// ---------------------------------------------------------------------------
// CSR build: histogram over all 3 relations in one launch
// ---------------------------------------------------------------------------
__global__ void count_all(const int* __restrict__ d0, const int* __restrict__ d1,
                          const int* __restrict__ d2, int* __restrict__ cnt,
                          int N, int n0, int n1, int n2) {
    int i = blockIdx.x * blockDim.x + threadIdx.x;
    int total = n0 + n1 + n2;
    if (i >= total) return;
    int r, j;
    if (i < n0)            { r = 0; j = i; }
    else if (i < n0 + n1)  { r = 1; j = i - n0; }
    else                   { r = 2; j = i - n0 - n1; }
    const int* d = (r == 0) ? d0 : (r == 1) ? d1 : d2;
    atomicAdd(&cnt[(size_t)r * N + d[j]], 1);
}

// block-local exclusive scan of cnt -> off, block totals -> bs
__global__ void scan1(const int* __restrict__ cnt, int* __restrict__ off,
                      int* __restrict__ bs, int N, int nchunks) {
    int r = blockIdx.y, c = blockIdx.x, tid = threadIdx.x;
    int i = c * SB + tid;
    __shared__ int s[SB];
    int v = (i < N) ? cnt[(size_t)r * N + i] : 0;
    s[tid] = v; __syncthreads();
    for (int d = 1; d < SB; d <<= 1) {
        int tv = (tid >= d) ? s[tid - d] : 0;
        __syncthreads();
        s[tid] += tv;
        __syncthreads();
    }
    if (i < N) off[(size_t)r * N + i] = s[tid] - v;     // exclusive within chunk
    if (tid == SB - 1) bs[r * nchunks + c] = s[tid];
}

// scan the chunk totals (nchunks <= 512)
__global__ void scan2(int* __restrict__ bs, int nchunks) {
    int r = blockIdx.x, tid = threadIdx.x;
    __shared__ int s[512];
    int v = (tid < nchunks) ? bs[r * nchunks + tid] : 0;
    s[tid] = v; __syncthreads();
    for (int d = 1; d < 512; d <<= 1) {
        int tv = (tid >= d) ? s[tid - d] : 0;
        __syncthreads();
        s[tid] += tv;
        __syncthreads();
    }
    if (tid < nchunks) bs[r * nchunks + tid] = s[tid] - v;  // exclusive
}

// add chunk offsets -> final exclusive offsets (fill_all will advance these)
__global__ void scan3(int* __restrict__ off, const int* __restrict__ bs,
                      int N, int nchunks) {
    int r = blockIdx.y;
    int i = blockIdx.x * SB + threadIdx.x;
    if (i < N) off[(size_t)r * N + i] += bs[r * nchunks + blockIdx.x];
}

// bucket-fill edge ids sorted by destination; atomics advance off in place
// (post-fill: off[i] = start_i + deg_i; gather recomputes start = off - deg)
__global__ void fill_all(const int* __restrict__ d0, const int* __restrict__ d1,
                         const int* __restrict__ d2, int* __restrict__ off,
                         int* __restrict__ eid, int N, int n0, int n1, int n2) {
    int i = blockIdx.x * blockDim.x + threadIdx.x;
    int total = n0 + n1 + n2;
    if (i >= total) return;
    int r, j, base;
    if (i < n0)            { r = 0; j = i;            base = 0; }
    else if (i < n0 + n1)  { r = 1; j = i - n0;       base = n0; }
    else                   { r = 2; j = i - n0 - n1;  base = n0 + n1; }
    const int* d = (r == 0) ? d0 : (r == 1) ? d1 : d2;
    int node = d[j];
    int p = atomicAdd(&off[(size_t)r * N + node], 1);
    eid[base + p] = j;
}

// ---------------------------------------------------------------------------
// Fused: gather-mean (CSR) + tanh-gate attention + projection.
// 256 threads = 8 groups x 32 lanes; each group owns TWO nodes.
// LDS trimmed to 24 KB: OY overwrites Ysh[ln][0] after softmax (wave-local
// program order makes this safe; no barriers anywhere).
// off[] holds start+deg after fill_all -> start = off - deg.
// ---------------------------------------------------------------------------
__global__ __launch_bounds__(256, 6) void node_fused(
        const float* __restrict__ E0, const float* __restrict__ E1,
        const float* __restrict__ E2,
        const int* __restrict__ eid,   // [sum nE], per-relation bases
        const int* __restrict__ off,   // [3,N]  (= start + deg)
        const int* __restrict__ cnt,   // [3,N]
        const float* __restrict__ W1, const float* __restrict__ W2,
        const float* __restrict__ W3,
        float* __restrict__ out, int N, int base1, int base2) {
    const int g = threadIdx.x >> 5;      // group 0..7
    const int t = threadIdx.x & 31;      // lane in group
    const int ln0 = g * 2;
    const int ln1 = ln0 + 1;

    __shared__ float Ysh[NPB][3][DE];    // 24 KB total

    const float* Es[3] = { E0, E1, E2 };
    const int ebase[3] = { 0, base1, base2 };

    // ---- gather + mean for the group's two nodes (loop NOT unrolled)
    #pragma unroll 1
    for (int n2 = 0; n2 < 2; ++n2) {
        const int ln = ln0 + n2;
        int node = blockIdx.x * NPB + ln;
        if (node >= N) node = N - 1;     // clamp; final stores are guarded

        #pragma unroll
        for (int r = 0; r < 3; ++r) {
            int deg   = cnt[(size_t)r * N + node];
            int start = off[(size_t)r * N + node] - deg;
            const int* el = eid + ebase[r] + start;
            const float* E = Es[r];
            f4 acc = {0.f, 0.f, 0.f, 0.f};

            int k = 0;
            for (; k + 8 <= deg; k += 8) {
                int e0 = el[k + 0], e1 = el[k + 1], e2 = el[k + 2], e3 = el[k + 3];
                int e4 = el[k + 4], e5 = el[k + 5], e6 = el[k + 6], e7 = el[k + 7];
                f4 v0 = __builtin_nontemporal_load(
                    reinterpret_cast<const f4*>(E + (size_t)e0 * DE + t * 4));
                f4 v1 = __builtin_nontemporal_load(
                    reinterpret_cast<const f4*>(E + (size_t)e1 * DE + t * 4));
                f4 v2 = __builtin_nontemporal_load(
                    reinterpret_cast<const f4*>(E + (size_t)e2 * DE + t * 4));
                f4 v3 = __builtin_nontemporal_load(
                    reinterpret_cast<const f4*>(E + (size_t)e3 * DE + t * 4));
                f4 v4 = __builtin_nontemporal_load(
                    reinterpret_cast<const f4*>(E + (size_t)e4 * DE + t * 4));
                f4 v5 = __builtin_nontemporal_load(
                    reinterpret_cast<const f4*>(E + (size_t)e5 * DE + t * 4));
                f4 v6 = __builtin_nontemporal_load(
                    reinterpret_cast<const f4*>(E + (size_t)e6 * DE + t * 4));
                f4 v7 = __builtin_nontemporal_load(
                    reinterpret_cast<const f4*>(E + (size_t)e7 * DE + t * 4));
                acc += ((v0 + v1) + (v2 + v3)) + ((v4 + v5) + (v6 + v7));
            }
            if (k + 4 <= deg) {
                int e0 = el[k + 0], e1 = el[k + 1], e2 = el[k + 2], e3 = el[k + 3];
                f4 v0 = __builtin_nontemporal_load(
                    reinterpret_cast<const f4*>(E + (size_t)e0 * DE + t * 4));
                f4 v1 = __builtin_nontemporal_load(
                    reinterpret_cast<const f4*>(E + (size_t)e1 * DE + t * 4));
                f4 v2 = __builtin_nontemporal_load(
                    reinterpret_cast<const f4*>(E + (size_t)e2 * DE + t * 4));
                f4 v3 = __builtin_nontemporal_load(
                    reinterpret_cast<const f4*>(E + (size_t)e3 * DE + t * 4));
                acc += (v0 + v1) + (v2 + v3);
                k += 4;
            }
            for (; k < deg; ++k) {
                int e = el[k];
                f4 v = __builtin_nontemporal_load(
                    reinterpret_cast<const f4*>(E + (size_t)e * DE + t * 4));
                acc += v;
            }

            float inv = 1.0f / fmaxf((float)deg, 1.0f);
            acc *= inv;
            *reinterpret_cast<f4*>(&Ysh[ln][r][t * 4]) = acc;
        }
    }

    // ---- z GEMM: 6 rows x 4 cols per thread; one f4 weight load -> 24 FMA
    f4 z0 = {0,0,0,0}, z1 = {0,0,0,0}, z2 = {0,0,0,0};
    f4 z3 = {0,0,0,0}, z4 = {0,0,0,0}, z5 = {0,0,0,0};
    {
        const float* w1p = W1 + t * 4;
        #pragma unroll 4
        for (int d = 0; d < DE; ++d) {
            f4 w = *reinterpret_cast<const f4*>(w1p + (size_t)d * DE);
            float a0 = Ysh[ln0][0][d], a1 = Ysh[ln0][1][d], a2 = Ysh[ln0][2][d];
            float b0 = Ysh[ln1][0][d], b1 = Ysh[ln1][1][d], b2 = Ysh[ln1][2][d];
            z0 += a0 * w; z1 += a1 * w; z2 += a2 * w;
            z3 += b0 * w; z4 += b1 * w; z5 += b2 * w;
        }
    }

    // ---- scores: e_q = sum_o tanh(z_q[o]) * W2[o]; reduce over 32 lanes
    f4 w2v = *reinterpret_cast<const f4*>(W2 + t * 4);
    float s0 = 0.f, s1 = 0.f, s2 = 0.f, s3 = 0.f, s4 = 0.f, s5 = 0.f;
    #pragma unroll
    for (int j = 0; j < 4; ++j) {
        s0 = fmaf(tanhf(z0[j]), w2v[j], s0);
        s1 = fmaf(tanhf(z1[j]), w2v[j], s1);
        s2 = fmaf(tanhf(z2[j]), w2v[j], s2);
        s3 = fmaf(tanhf(z3[j]), w2v[j], s3);
        s4 = fmaf(tanhf(z4[j]), w2v[j], s4);
        s5 = fmaf(tanhf(z5[j]), w2v[j], s5);
    }
    #pragma unroll
    for (int m = 16; m >= 1; m >>= 1) {
        s0 += __shfl_xor(s0, m); s1 += __shfl_xor(s1, m); s2 += __shfl_xor(s2, m);
        s3 += __shfl_xor(s3, m); s4 += __shfl_xor(s4, m); s5 += __shfl_xor(s5, m);
    }

    // ---- softmax per node; OY overwrites Ysh[ln][0] (cols 4t..4t+3)
    {
        float mx = fmaxf(s0, fmaxf(s1, s2));
        float x0 = __expf(s0 - mx), x1 = __expf(s1 - mx), x2 = __expf(s2 - mx);
        float inv = 1.0f / (x0 + x1 + x2);
        f4 y0 = *reinterpret_cast<const f4*>(&Ysh[ln0][0][t * 4]);
        f4 y1 = *reinterpret_cast<const f4*>(&Ysh[ln0][1][t * 4]);
        f4 y2 = *reinterpret_cast<const f4*>(&Ysh[ln0][2][t * 4]);
        f4 oy = (x0 * inv) * y0 + (x1 * inv) * y1 + (x2 * inv) * y2;
        *reinterpret_cast<f4*>(&Ysh[ln0][0][t * 4]) = oy;
    }
    {
        float mx = fmaxf(s3, fmaxf(s4, s5));
        float x0 = __expf(s3 - mx), x1 = __expf(s4 - mx), x2 = __expf(s5 - mx);
        float inv = 1.0f / (x0 + x1 + x2);
        f4 y0 = *reinterpret_cast<const f4*>(&Ysh[ln1][0][t * 4]);
        f4 y1 = *reinterpret_cast<const f4*>(&Ysh[ln1][1][t * 4]);
        f4 y2 = *reinterpret_cast<const f4*>(&Ysh[ln1][2][t * 4]);
        f4 oy = (x0 * inv) * y0 + (x1 * inv) * y1 + (x2 * inv) * y2;
        *reinterpret_cast<f4*>(&Ysh[ln1][0][t * 4]) = oy;
    }

    // ---- out = OY @ W3, both nodes per weight load (OY lives in Ysh[.][0])
    f4 o0 = {0,0,0,0}, o1 = {0,0,0,0};
    {
        const float* w3p = W3 + t * 4;
        #pragma unroll 4
        for (int d = 0; d < DE; ++d) {
            f4 w = *reinterpret_cast<const f4*>(w3p + (size_t)d * DE);
            float a = Ysh[ln0][0][d];
            float b = Ysh[ln1][0][d];
            o0 += a * w;
            o1 += b * w;
        }
    }
    {
        int node0 = blockIdx.x * NPB + ln0;
        int node1 = node0 + 1;
        if (node0 < N)
            *reinterpret_cast<f4*>(out + (size_t)node0 * DE + t * 4) = o0;
        if (node1 < N)
            *reinterpret_cast<f4*>(out + (size_t)node1 * DE + t * 4) = o1;
    }
}

// ---------------------------------------------------------------------------
// launch
// ---------------------------------------------------------------------------
extern "C" void kernel_launch(void* const* d_in, const int* in_sizes, int n_in,
                              void* d_out, int out_size, void* d_ws, size_t ws_size,
                              hipStream_t stream) {
    const float* E_C = (const float*)d_in[0];
    const float* E_D = (const float*)d_in[1];
    const float* E_M = (const float*)d_in[2];
    const int* dst_C = (const int*)d_in[3];
    const int* dst_D = (const int*)d_in[4];
    const int* dst_M = (const int*)d_in[5];
    const float* W1 = (const float*)d_in[7];
    const float* W2 = (const float*)d_in[8];
    const float* W3 = (const float*)d_in[9];
    float* out = (float*)d_out;

    const int N = out_size / DE;                     // 100000
    const int nE[3] = { in_sizes[3], in_sizes[4], in_sizes[5] };
    const int NEtot = nE[0] + nE[1] + nE[2];
    const int nchunks = (N + SB - 1) / SB;           // 391 for N=100000

    // workspace (ints): eid[NEtot] | cnt[3N] | off[3N] | bs[3*nchunks]
    int* eid = (int*)d_ws;
    int* cnt = eid + NEtot;
    int* off = cnt + 3 * (size_t)N;
    int* bs  = off + 3 * (size_t)N;

    (void)hipMemsetAsync(cnt, 0, 3 * (size_t)N * sizeof(int), stream);

    {
        int blocks = (NEtot + 255) / 256;
        count_all<<<blocks, 256, 0, stream>>>(dst_C, dst_D, dst_M, cnt,
                                              N, nE[0], nE[1], nE[2]);
    }

    dim3 g1(nchunks, 3);
    scan1<<<g1, SB, 0, stream>>>(cnt, off, bs, N, nchunks);
    scan2<<<3, 512, 0, stream>>>(bs, nchunks);
    scan3<<<g1, SB, 0, stream>>>(off, bs, N, nchunks);

    {
        int blocks = (NEtot + 255) / 256;
        fill_all<<<blocks, 256, 0, stream>>>(dst_C, dst_D, dst_M, off, eid,
                                             N, nE[0], nE[1], nE[2]);
    }

    int nblocks = (N + NPB - 1) / NPB;
    node_fused<<<nblocks, 256, 0, stream>>>(
        E_C, E_D, E_M, eid, off, cnt, W1, W2, W3, out,
        N, nE[0], nE[0] + nE[1]);
}

// Round 11
// 745.358 us; speedup vs baseline: 2.8767x; 1.1486x over previous
//
#include <hip/hip_runtime.h>
#include <hip/hip_bf16.h>

#define DE 128
#define NPB 16          // nodes per block (8 groups x 2 nodes, gathered serially)
#define CAP 64          // fixed bucket capacity per (relation, node); Poisson(10) tail @64 ~ 1e-30

typedef float f4 __attribute__((ext_vector_type(4)));

// ---------------------------------------------------------------------------
// One-pass bucket fill: replaces count + scan x3 + fill (R10 residual was
// ~365 us of dependent mini-launches). cnt counts true degree; slot via the
// same atomic. eid[(r*N+node)*CAP + p] = edge id.
// ---------------------------------------------------------------------------
__global__ void fill_direct(const int* __restrict__ d0, const int* __restrict__ d1,
                            const int* __restrict__ d2, int* __restrict__ cnt,
                            int* __restrict__ eid, int N, int n0, int n1, int n2) {
    int i = blockIdx.x * blockDim.x + threadIdx.x;
    int total = n0 + n1 + n2;
    if (i >= total) return;
    int r, j;
    if (i < n0)            { r = 0; j = i; }
    else if (i < n0 + n1)  { r = 1; j = i - n0; }
    else                   { r = 2; j = i - n0 - n1; }
    const int* d = (r == 0) ? d0 : (r == 1) ? d1 : d2;
    int node = d[j];
    size_t slot = (size_t)r * N + node;
    int p = atomicAdd(&cnt[slot], 1);
    if (p < CAP) eid[(slot << 6) + p] = j;
}

// ---------------------------------------------------------------------------
// Fused: gather-mean (bucketed lists) + tanh-gate attention + projection.
// 256 threads = 8 groups x 32 lanes; each group owns TWO nodes.
// LDS 24 KB (OY overwrites Ysh[ln][0] after softmax; wave-local, no barriers).
// ---------------------------------------------------------------------------
__global__ __launch_bounds__(256, 6) void node_fused(
        const float* __restrict__ E0, const float* __restrict__ E1,
        const float* __restrict__ E2,
        const int* __restrict__ eid,   // [3*N*CAP]
        const int* __restrict__ cnt,   // [3,N]
        const float* __restrict__ W1, const float* __restrict__ W2,
        const float* __restrict__ W3,
        float* __restrict__ out, int N) {
    const int g = threadIdx.x >> 5;      // group 0..7
    const int t = threadIdx.x & 31;      // lane in group
    const int ln0 = g * 2;
    const int ln1 = ln0 + 1;

    __shared__ float Ysh[NPB][3][DE];    // 24 KB total

    const float* Es[3] = { E0, E1, E2 };

    // ---- gather + mean for the group's two nodes (loop NOT unrolled)
    #pragma unroll 1
    for (int n2 = 0; n2 < 2; ++n2) {
        const int ln = ln0 + n2;
        int node = blockIdx.x * NPB + ln;
        if (node >= N) node = N - 1;     // clamp; final stores are guarded

        #pragma unroll
        for (int r = 0; r < 3; ++r) {
            size_t slot = (size_t)r * N + node;
            int deg = cnt[slot];
            const int* el = eid + (slot << 6);
            const float* E = Es[r];
            f4 acc = {0.f, 0.f, 0.f, 0.f};

            int k = 0;
            for (; k + 8 <= deg; k += 8) {
                int e0 = el[k + 0], e1 = el[k + 1], e2 = el[k + 2], e3 = el[k + 3];
                int e4 = el[k + 4], e5 = el[k + 5], e6 = el[k + 6], e7 = el[k + 7];
                f4 v0 = __builtin_nontemporal_load(
                    reinterpret_cast<const f4*>(E + (size_t)e0 * DE + t * 4));
                f4 v1 = __builtin_nontemporal_load(
                    reinterpret_cast<const f4*>(E + (size_t)e1 * DE + t * 4));
                f4 v2 = __builtin_nontemporal_load(
                    reinterpret_cast<const f4*>(E + (size_t)e2 * DE + t * 4));
                f4 v3 = __builtin_nontemporal_load(
                    reinterpret_cast<const f4*>(E + (size_t)e3 * DE + t * 4));
                f4 v4 = __builtin_nontemporal_load(
                    reinterpret_cast<const f4*>(E + (size_t)e4 * DE + t * 4));
                f4 v5 = __builtin_nontemporal_load(
                    reinterpret_cast<const f4*>(E + (size_t)e5 * DE + t * 4));
                f4 v6 = __builtin_nontemporal_load(
                    reinterpret_cast<const f4*>(E + (size_t)e6 * DE + t * 4));
                f4 v7 = __builtin_nontemporal_load(
                    reinterpret_cast<const f4*>(E + (size_t)e7 * DE + t * 4));
                acc += ((v0 + v1) + (v2 + v3)) + ((v4 + v5) + (v6 + v7));
            }
            if (k + 4 <= deg) {
                int e0 = el[k + 0], e1 = el[k + 1], e2 = el[k + 2], e3 = el[k + 3];
                f4 v0 = __builtin_nontemporal_load(
                    reinterpret_cast<const f4*>(E + (size_t)e0 * DE + t * 4));
                f4 v1 = __builtin_nontemporal_load(
                    reinterpret_cast<const f4*>(E + (size_t)e1 * DE + t * 4));
                f4 v2 = __builtin_nontemporal_load(
                    reinterpret_cast<const f4*>(E + (size_t)e2 * DE + t * 4));
                f4 v3 = __builtin_nontemporal_load(
                    reinterpret_cast<const f4*>(E + (size_t)e3 * DE + t * 4));
                acc += (v0 + v1) + (v2 + v3);
                k += 4;
            }
            for (; k < deg; ++k) {
                int e = el[k];
                f4 v = __builtin_nontemporal_load(
                    reinterpret_cast<const f4*>(E + (size_t)e * DE + t * 4));
                acc += v;
            }

            float inv = 1.0f / fmaxf((float)deg, 1.0f);
            acc *= inv;
            *reinterpret_cast<f4*>(&Ysh[ln][r][t * 4]) = acc;
        }
    }

    // ---- z GEMM: 6 rows x 4 cols per thread; one f4 weight load -> 24 FMA
    f4 z0 = {0,0,0,0}, z1 = {0,0,0,0}, z2 = {0,0,0,0};
    f4 z3 = {0,0,0,0}, z4 = {0,0,0,0}, z5 = {0,0,0,0};
    {
        const float* w1p = W1 + t * 4;
        #pragma unroll 4
        for (int d = 0; d < DE; ++d) {
            f4 w = *reinterpret_cast<const f4*>(w1p + (size_t)d * DE);
            float a0 = Ysh[ln0][0][d], a1 = Ysh[ln0][1][d], a2 = Ysh[ln0][2][d];
            float b0 = Ysh[ln1][0][d], b1 = Ysh[ln1][1][d], b2 = Ysh[ln1][2][d];
            z0 += a0 * w; z1 += a1 * w; z2 += a2 * w;
            z3 += b0 * w; z4 += b1 * w; z5 += b2 * w;
        }
    }

    // ---- scores: e_q = sum_o tanh(z_q[o]) * W2[o]; reduce over 32 lanes
    f4 w2v = *reinterpret_cast<const f4*>(W2 + t * 4);
    float s0 = 0.f, s1 = 0.f, s2 = 0.f, s3 = 0.f, s4 = 0.f, s5 = 0.f;
    #pragma unroll
    for (int j = 0; j < 4; ++j) {
        s0 = fmaf(tanhf(z0[j]), w2v[j], s0);
        s1 = fmaf(tanhf(z1[j]), w2v[j], s1);
        s2 = fmaf(tanhf(z2[j]), w2v[j], s2);
        s3 = fmaf(tanhf(z3[j]), w2v[j], s3);
        s4 = fmaf(tanhf(z4[j]), w2v[j], s4);
        s5 = fmaf(tanhf(z5[j]), w2v[j], s5);
    }
    #pragma unroll
    for (int m = 16; m >= 1; m >>= 1) {
        s0 += __shfl_xor(s0, m); s1 += __shfl_xor(s1, m); s2 += __shfl_xor(s2, m);
        s3 += __shfl_xor(s3, m); s4 += __shfl_xor(s4, m); s5 += __shfl_xor(s5, m);
    }

    // ---- softmax per node; OY overwrites Ysh[ln][0] (cols 4t..4t+3)
    {
        float mx = fmaxf(s0, fmaxf(s1, s2));
        float x0 = __expf(s0 - mx), x1 = __expf(s1 - mx), x2 = __expf(s2 - mx);
        float inv = 1.0f / (x0 + x1 + x2);
        f4 y0 = *reinterpret_cast<const f4*>(&Ysh[ln0][0][t * 4]);
        f4 y1 = *reinterpret_cast<const f4*>(&Ysh[ln0][1][t * 4]);
        f4 y2 = *reinterpret_cast<const f4*>(&Ysh[ln0][2][t * 4]);
        f4 oy = (x0 * inv) * y0 + (x1 * inv) * y1 + (x2 * inv) * y2;
        *reinterpret_cast<f4*>(&Ysh[ln0][0][t * 4]) = oy;
    }
    {
        float mx = fmaxf(s3, fmaxf(s4, s5));
        float x0 = __expf(s3 - mx), x1 = __expf(s4 - mx), x2 = __expf(s5 - mx);
        float inv = 1.0f / (x0 + x1 + x2);
        f4 y0 = *reinterpret_cast<const f4*>(&Ysh[ln1][0][t * 4]);
        f4 y1 = *reinterpret_cast<const f4*>(&Ysh[ln1][1][t * 4]);
        f4 y2 = *reinterpret_cast<const f4*>(&Ysh[ln1][2][t * 4]);
        f4 oy = (x0 * inv) * y0 + (x1 * inv) * y1 + (x2 * inv) * y2;
        *reinterpret_cast<f4*>(&Ysh[ln1][0][t * 4]) = oy;
    }

    // ---- out = OY @ W3, both nodes per weight load (OY lives in Ysh[.][0])
    f4 o0 = {0,0,0,0}, o1 = {0,0,0,0};
    {
        const float* w3p = W3 + t * 4;
        #pragma unroll 4
        for (int d = 0; d < DE; ++d) {
            f4 w = *reinterpret_cast<const f4*>(w3p + (size_t)d * DE);
            float a = Ysh[ln0][0][d];
            float b = Ysh[ln1][0][d];
            o0 += a * w;
            o1 += b * w;
        }
    }
    {
        int node0 = blockIdx.x * NPB + ln0;
        int node1 = node0 + 1;
        if (node0 < N)
            *reinterpret_cast<f4*>(out + (size_t)node0 * DE + t * 4) = o0;
        if (node1 < N)
            *reinterpret_cast<f4*>(out + (size_t)node1 * DE + t * 4) = o1;
    }
}

// ---------------------------------------------------------------------------
// launch
// ---------------------------------------------------------------------------
extern "C" void kernel_launch(void* const* d_in, const int* in_sizes, int n_in,
                              void* d_out, int out_size, void* d_ws, size_t ws_size,
                              hipStream_t stream) {
    const float* E_C = (const float*)d_in[0];
    const float* E_D = (const float*)d_in[1];
    const float* E_M = (const float*)d_in[2];
    const int* dst_C = (const int*)d_in[3];
    const int* dst_D = (const int*)d_in[4];
    const int* dst_M = (const int*)d_in[5];
    const float* W1 = (const float*)d_in[7];
    const float* W2 = (const float*)d_in[8];
    const float* W3 = (const float*)d_in[9];
    float* out = (float*)d_out;

    const int N = out_size / DE;                     // 100000
    const int nE[3] = { in_sizes[3], in_sizes[4], in_sizes[5] };
    const int NEtot = nE[0] + nE[1] + nE[2];

    // workspace (ints): eid[3*N*CAP] (76.8 MB) | cnt[3N]
    int* eid = (int*)d_ws;
    int* cnt = eid + (size_t)3 * N * CAP;

    (void)hipMemsetAsync(cnt, 0, 3 * (size_t)N * sizeof(int), stream);

    {
        int blocks = (NEtot + 255) / 256;
        fill_direct<<<blocks, 256, 0, stream>>>(dst_C, dst_D, dst_M, cnt, eid,
                                                N, nE[0], nE[1], nE[2]);
    }

    int nblocks = (N + NPB - 1) / NPB;
    node_fused<<<nblocks, 256, 0, stream>>>(
        E_C, E_D, E_M, eid, cnt, W1, W2, W3, out, N);
}